// Round 16
// baseline (99.303 us; speedup 1.0000x reference)
//
#include <hip/hip_runtime.h>
#include <stdint.h>

// ImportanceSparsification: per-batch top-k (k = 0.2*S*T) of 1/(cost+1e-8),
// out = (source, target, cost*mask). Exact selection with jax top_k
// tie-break (lowest flat index among equal importance values).
//
// R15 -> R16: accounting across rounds showed (a) R8's SEQUENTIAL
// homogeneous dispatches beat all merged-role variants (heterogeneous
// co-resident blocks interfere), and (b) the provisional+fixup machinery
// only avoided an L3-resident re-read (timed-replay FETCH ~21MB) -> worth
// nothing. R16 = R8 skeleton, modernized:
//   1. gather: PURE-READ (register below-count, rare window staging),
//      per-block private outputs -> no global atomics, no init dispatch.
//   2. solve: R15's slim LDS-staged threshold+tie; thr/idxthr valid on
//      both hit and miss paths.
//   3. final: uniform 1-f4/thread exact mask + fused src/tgt copies.
// 3 dispatches total.

static constexpr int LCAP  = 512;     // per-G-block candidate region
static constexpr int SCAP  = 6656;    // solve: LDS staged candidate cap
static constexpr int TIECAP = 2048;   // solve: LDS tie list / slow hist
static constexpr int HBINS = 512;     // linear cost bins
static constexpr int NT    = 512;     // solve block size
static constexpr int NW    = NT / 64; // waves in solve block
static constexpr int GPB   = 64;      // gather blocks per batch
static constexpr uint32_t SPEC_LO = 100;  // speculative window (bins of 512)
static constexpr uint32_t SPEC_HI = 104;
static constexpr float EPSF = 1e-8f;

__device__ __forceinline__ uint32_t impBits(float c) {
    // IEEE-correct f32 ops (no fast-math) -> bit-exact vs numpy reference
    return __float_as_uint(1.0f / (c + EPSF));
}

__device__ __forceinline__ uint32_t costBin(float x) {
    uint32_t bi = (uint32_t)(x * (float)HBINS);  // x in [0,1)
    return bi > (HBINS - 1) ? (HBINS - 1) : bi;
}

// per-G-block record (8 u32): [0]=below [1..5]=win[5] [6]=cnt [7]=overflow
// meta per batch (8 u32): [0]=thr [1]=idxthr  (written by solve)

// ---- pass 1: pure-read gather: below/win counts + window candidates ----
__global__ __launch_bounds__(256) void gather_kernel(
    const float4* __restrict__ cost4, uint32_t* __restrict__ bcnt,
    uint32_t* __restrict__ candv, uint32_t* __restrict__ candi, int n4) {
    __shared__ uint32_t l_cv[LCAP];
    __shared__ uint32_t l_ci[LCAP];
    __shared__ uint32_t lh_win[5];
    __shared__ uint32_t l_below[4];
    __shared__ uint32_t l_cnt;
    const int bid = blockIdx.x;
    const int tid = threadIdx.x;
    const int b = bid >> 6;          // GPB = 64
    const int x = bid & (GPB - 1);
    const int w = tid >> 6, ln = tid & 63;
    if (tid < 5) lh_win[tid] = 0;
    if (tid == 0) l_cnt = 0;
    __syncthreads();
    const size_t base4 = (size_t)b * n4 + (size_t)x * 4096;
    uint32_t below = 0;
    #pragma unroll
    for (int r = 0; r < 4; ++r) {
        const size_t r0 = base4 + (size_t)r * 1024;
        float4 v0 = cost4[r0 + 0 * 256 + tid];
        float4 v1 = cost4[r0 + 1 * 256 + tid];
        float4 v2 = cost4[r0 + 2 * 256 + tid];
        float4 v3 = cost4[r0 + 3 * 256 + tid];
        uint32_t bb[16];
        bb[0]  = costBin(v0.x); bb[1]  = costBin(v0.y); bb[2]  = costBin(v0.z); bb[3]  = costBin(v0.w);
        bb[4]  = costBin(v1.x); bb[5]  = costBin(v1.y); bb[6]  = costBin(v1.z); bb[7]  = costBin(v1.w);
        bb[8]  = costBin(v2.x); bb[9]  = costBin(v2.y); bb[10] = costBin(v2.z); bb[11] = costBin(v2.w);
        bb[12] = costBin(v3.x); bb[13] = costBin(v3.y); bb[14] = costBin(v3.z); bb[15] = costBin(v3.w);
        uint32_t hm = 0;
        #pragma unroll
        for (int k = 0; k < 16; ++k) {
            below += (bb[k] < SPEC_LO) ? 1u : 0u;
            hm |= ((uint32_t)(bb[k] >= SPEC_LO && bb[k] <= SPEC_HI)) << k;
        }
        if (hm) {
            const float vals[16] = {v0.x, v0.y, v0.z, v0.w, v1.x, v1.y, v1.z, v1.w,
                                    v2.x, v2.y, v2.z, v2.w, v3.x, v3.y, v3.z, v3.w};
            while (hm) {
                const int k = __ffs(hm) - 1;
                hm &= hm - 1;
                atomicAdd(&lh_win[bb[k] - SPEC_LO], 1u);
                const uint32_t p = atomicAdd(&l_cnt, 1u);
                if (p < (uint32_t)LCAP) {
                    l_cv[p] = __float_as_uint(vals[k]);
                    l_ci[p] = ((uint32_t)x * 4096u + (uint32_t)r * 1024u +
                               ((uint32_t)(k >> 2)) * 256u + (uint32_t)tid) * 4u +
                              (uint32_t)(k & 3);
                }
            }
        }
    }
    #pragma unroll
    for (int o = 1; o < 64; o <<= 1) below += (uint32_t)__shfl_xor((int)below, o);
    if (ln == 0) l_below[w] = below;
    __syncthreads();
    const uint32_t tot = l_cnt;
    const uint32_t n = (tot > (uint32_t)LCAP) ? (uint32_t)LCAP : tot;
    if (tid == 0) {
        uint32_t* r = bcnt + (size_t)bid * 8;
        r[0] = l_below[0] + l_below[1] + l_below[2] + l_below[3];
        r[6] = n;
        r[7] = (tot > (uint32_t)LCAP) ? 1u : 0u;
    }
    if (tid >= 64 && tid < 69) bcnt[(size_t)bid * 8 + 1 + (tid - 64)] = lh_win[tid - 64];
    uint32_t* cv = candv + (size_t)bid * LCAP;
    uint32_t* ci = candi + (size_t)bid * LCAP;
    for (uint32_t i = tid; i < n; i += 256) { cv[i] = l_cv[i]; ci[i] = l_ci[i]; }
}

// ---- pass 2: validate + LDS-staged exact threshold + tie index ----
__global__ __launch_bounds__(NT) void solve_kernel(
    const uint32_t* __restrict__ bcnt, uint32_t* __restrict__ meta,
    const uint32_t* __restrict__ candv, const uint32_t* __restrict__ candi,
    const float4* __restrict__ cost4, int n4, uint32_t K, int N) {
    const int b = blockIdx.x;
    __shared__ uint32_t scv[SCAP];
    __shared__ uint32_t sci[SCAP];
    __shared__ uint32_t hh[TIECAP];
    __shared__ uint32_t pref[HBINS];
    __shared__ uint32_t sw[4 * NW];
    __shared__ uint32_t s_q, s_lo, s_need, s_range, s_scnt, s_res;
    __shared__ uint32_t s_below, s_win[5], s_over;
    const int t = threadIdx.x;
    const int w = t >> 6, ln = t & 63;

    // -- aggregate per-block records (wave 0: 64 regions, one per lane) --
    if (w == 0) {
        const uint32_t* r = bcnt + (size_t)(b * GPB + ln) * 8;
        uint32_t bl = r[0], w0 = r[1], w1 = r[2], w2 = r[3], w3 = r[4],
                 w4 = r[5], ov = r[7];
        #pragma unroll
        for (int o = 1; o < 64; o <<= 1) {
            bl += (uint32_t)__shfl_xor((int)bl, o);
            w0 += (uint32_t)__shfl_xor((int)w0, o);
            w1 += (uint32_t)__shfl_xor((int)w1, o);
            w2 += (uint32_t)__shfl_xor((int)w2, o);
            w3 += (uint32_t)__shfl_xor((int)w3, o);
            w4 += (uint32_t)__shfl_xor((int)w4, o);
            ov |= (uint32_t)__shfl_xor((int)ov, o);
        }
        if (ln == 0) {
            s_below = bl; s_win[0] = w0; s_win[1] = w1; s_win[2] = w2;
            s_win[3] = w3; s_win[4] = w4; s_over = ov;
        }
    }
    if (t == 0) s_scnt = 0;
    __syncthreads();
    const uint32_t below = s_below;
    const uint32_t over = s_over;
    uint32_t win[5];
    #pragma unroll
    for (int i = 0; i < 5; ++i) win[i] = s_win[i];
    int qrel = -1;
    {
        uint32_t cum = below;
        if (K <= cum) qrel = -1;
        else {
            qrel = 5;
            #pragma unroll
            for (int i = 0; i < 5; ++i) {
                if (K > cum && K <= cum + win[i]) { qrel = i; break; }
                cum += win[i];
            }
        }
    }
    const bool hit = (qrel >= 1 && qrel <= 3) && !over;

    uint32_t need0;
    if (hit) {
        // stage bins [q-1, q+1] from the 64 per-block regions into LDS
        const uint32_t q = SPEC_LO + (uint32_t)qrel;
        uint32_t wb = 0;
        for (int i = 0; i < qrel - 1; ++i) wb += win[i];
        need0 = K - below - wb;
        for (int r = 0; r < GPB; ++r) {
            const uint32_t cnt_r = bcnt[(size_t)(b * GPB + r) * 8 + 6];
            const uint32_t* cv = candv + (size_t)(b * GPB + r) * LCAP;
            const uint32_t* ci = candi + (size_t)(b * GPB + r) * LCAP;
            for (uint32_t j = t; j < cnt_r; j += NT) {
                const uint32_t v = cv[j];
                const uint32_t bi = costBin(__uint_as_float(v));
                const bool p = (bi + 1 >= q) && (bi <= q + 1);
                const uint64_t mk = __ballot(p);
                if (p) {
                    const int leader = __ffsll((long long)mk) - 1;
                    const uint32_t rank = (uint32_t)__popcll(mk & ((1ull << ln) - 1ull));
                    uint32_t base = 0;
                    if (ln == leader) base = atomicAdd(&s_scnt, (uint32_t)__popcll(mk));
                    base = (uint32_t)__shfl((int)base, leader);
                    const uint32_t pos = base + rank;
                    if (pos < (uint32_t)SCAP) { scv[pos] = v; sci[pos] = ci[j]; }
                }
            }
        }
        __syncthreads();
    } else {
        // slow path (not taken for uniform data): full 512-bin hist,
        // locate crossing bin, stage [q-1, q+1] directly from cost
        for (int i = t; i < HBINS; i += NT) hh[i] = 0;
        __syncthreads();
        for (uint32_t i4 = (uint32_t)t; i4 < (uint32_t)n4; i4 += NT) {
            const float4 v = cost4[(size_t)b * n4 + i4];
            atomicAdd(&hh[costBin(v.x)], 1u);
            atomicAdd(&hh[costBin(v.y)], 1u);
            atomicAdd(&hh[costBin(v.z)], 1u);
            atomicAdd(&hh[costBin(v.w)], 1u);
        }
        __syncthreads();
        const uint32_t hv = hh[t];
        uint32_t incl = hv;
        #pragma unroll
        for (int o = 1; o < 64; o <<= 1) {
            const uint32_t u = (uint32_t)__shfl_up((int)incl, o);
            if (ln >= o) incl += u;
        }
        if (ln == 63) sw[w] = incl;
        if (t == 0) s_q = HBINS - 1;
        __syncthreads();
        uint32_t wbase = 0;
        for (int i = 0; i < w; ++i) wbase += sw[i];
        incl += wbase;
        pref[t] = incl;
        __syncthreads();
        if (K > incl - hv && K <= incl) s_q = (uint32_t)t;
        __syncthreads();
        const uint32_t q = s_q;
        const uint32_t lob = (q > 0) ? q - 1 : 0;
        const uint32_t hib = (q < HBINS - 1) ? q + 1 : (HBINS - 1);
        need0 = K - ((lob > 0) ? pref[lob - 1] : 0u);
        for (uint32_t i4 = (uint32_t)t; i4 < (uint32_t)n4; i4 += NT) {
            const float4 v = cost4[(size_t)b * n4 + i4];
            const float xx[4] = {v.x, v.y, v.z, v.w};
            #pragma unroll
            for (int j = 0; j < 4; ++j) {
                const uint32_t bi = costBin(xx[j]);
                const bool p = (bi >= lob && bi <= hib);
                const uint64_t mk = __ballot(p);
                if (p) {
                    const int leader = __ffsll((long long)mk) - 1;
                    const uint32_t rank = (uint32_t)__popcll(mk & ((1ull << ln) - 1ull));
                    uint32_t base = 0;
                    if (ln == leader) base = atomicAdd(&s_scnt, (uint32_t)__popcll(mk));
                    base = (uint32_t)__shfl((int)base, leader);
                    const uint32_t pos = base + rank;
                    if (pos < (uint32_t)SCAP) {
                        scv[pos] = __float_as_uint(xx[j]);
                        sci[pos] = i4 * 4u + (uint32_t)j;
                    }
                }
            }
        }
        __syncthreads();
    }
    const uint32_t scnt = (s_scnt > (uint32_t)SCAP) ? (uint32_t)SCAP : s_scnt;

    // -- block min/max of staged cost bits --
    uint32_t mn = 0xFFFFFFFFu, mx = 0u;
    for (uint32_t j = t; j < scnt; j += NT) {
        const uint32_t v = scv[j];
        mn = (v < mn) ? v : mn;
        mx = (v > mx) ? v : mx;
    }
    #pragma unroll
    for (int o = 1; o < 64; o <<= 1) {
        const uint32_t a = (uint32_t)__shfl_xor((int)mn, o);
        const uint32_t z = (uint32_t)__shfl_xor((int)mx, o);
        mn = (a < mn) ? a : mn;
        mx = (z > mx) ? z : mx;
    }
    if (ln == 0) { sw[w] = mn; sw[NW + w] = mx; }
    __syncthreads();
    uint32_t lo = sw[0], hix = sw[NW];
    #pragma unroll
    for (int i = 1; i < NW; ++i) {
        lo = (sw[i] < lo) ? sw[i] : lo;
        hix = (sw[NW + i] > hix) ? sw[NW + i] : hix;
    }
    uint32_t range = hix - lo + 1u;
    uint32_t need = need0;

    // -- histogram descent over LDS staged set --
    while (range > 1u) {
        const int bits = 32 - __clz((int)(range - 1u));
        const int shift = (bits > 11) ? (bits - 11) : 0;
        for (int i = t; i < TIECAP; i += NT) hh[i] = 0;
        __syncthreads();
        for (uint32_t j = t; j < scnt; j += NT) {
            const uint32_t v = scv[j];
            const uint32_t d = v - lo;
            if (v >= lo && d < range) atomicAdd(&hh[d >> shift], 1u);
        }
        __syncthreads();
        uint32_t hv4[4];
        uint32_t csum = 0;
        #pragma unroll
        for (int i = 0; i < 4; ++i) { hv4[i] = hh[t * 4 + i]; csum += hv4[i]; }
        uint32_t inc2 = csum;
        #pragma unroll
        for (int o = 1; o < 64; o <<= 1) {
            const uint32_t up = (uint32_t)__shfl_up((int)inc2, o);
            if (ln >= o) inc2 += up;
        }
        if (ln == 63) sw[w] = inc2;
        if (t == 0) { s_lo = lo; s_need = 1u; s_range = 1u; }
        __syncthreads();
        uint32_t wpre = 0;
        for (int i = 0; i < w; ++i) wpre += sw[i];
        const uint32_t before = wpre + inc2 - csum;
        if (before < need && before + csum >= need) {
            uint32_t cum = before;
            #pragma unroll
            for (int i = 0; i < 4; ++i) {
                if (cum + hv4[i] >= need) {
                    const uint32_t qq = (uint32_t)(t * 4 + i);
                    const uint32_t off = qq << shift;
                    s_lo = lo + off;
                    s_need = need - cum;
                    const uint32_t span = range - off;
                    s_range = (span < (1u << shift)) ? span : (1u << shift);
                    break;
                }
                cum += hv4[i];
            }
        }
        __syncthreads();
        lo = s_lo; need = s_need; range = s_range;
        __syncthreads();
    }
    const uint32_t thr = impBits(__uint_as_float(lo));

    // -- count gt/eq; min/max tie index (LDS only) --
    uint32_t cg = 0, ce = 0, imn = 0xFFFFFFFFu, imx = 0u;
    for (uint32_t j = t; j < scnt; j += NT) {
        const uint32_t ib = impBits(__uint_as_float(scv[j]));
        if (ib > thr) cg++;
        else if (ib == thr) {
            ce++;
            const uint32_t ix = sci[j];
            imn = (ix < imn) ? ix : imn;
            imx = (ix > imx) ? ix : imx;
        }
    }
    #pragma unroll
    for (int o = 1; o < 64; o <<= 1) {
        cg += (uint32_t)__shfl_xor((int)cg, o);
        ce += (uint32_t)__shfl_xor((int)ce, o);
        const uint32_t a = (uint32_t)__shfl_xor((int)imn, o);
        const uint32_t z = (uint32_t)__shfl_xor((int)imx, o);
        imn = (a < imn) ? a : imn;
        imx = (z > imx) ? z : imx;
    }
    if (ln == 0) { sw[w] = cg; sw[NW + w] = ce; sw[2 * NW + w] = imn; sw[3 * NW + w] = imx; }
    __syncthreads();
    uint32_t gt = 0, eq = 0, imin = 0xFFFFFFFFu, imax = 0u;
    #pragma unroll
    for (int i = 0; i < NW; ++i) {
        gt += sw[i];
        eq += sw[NW + i];
        imin = (sw[2 * NW + i] < imin) ? sw[2 * NW + i] : imin;
        imax = (sw[3 * NW + i] > imax) ? sw[3 * NW + i] : imax;
    }
    __syncthreads();

    const uint32_t m = need0 - gt;  // # threshold-equal elements to take
    uint32_t idxthr = 0xFFFFFFFFu;
    if (m < eq) {
        if (m == 1) {
            idxthr = imin;
        } else {
            if (t == 0) { s_scnt = 0; s_res = imin; }
            __syncthreads();
            for (uint32_t j = t; j < scnt; j += NT) {
                if (impBits(__uint_as_float(scv[j])) == thr) {
                    const uint32_t p = atomicAdd(&s_scnt, 1u);
                    if (p < (uint32_t)TIECAP) hh[p] = sci[j];
                }
            }
            __syncthreads();
            const uint32_t tc = s_scnt;
            if (tc <= (uint32_t)TIECAP) {
                for (uint32_t p = t; p < tc; p += NT) {
                    const uint32_t x = hh[p];
                    uint32_t r = 0;
                    for (uint32_t q2 = 0; q2 < tc; ++q2) r += (hh[q2] < x) ? 1u : 0u;
                    if (r == m - 1) s_res = x;
                }
                __syncthreads();
                idxthr = s_res;
            } else {
                uint32_t l2 = imin, h2 = imax;
                while (l2 < h2) {
                    const uint32_t mid = l2 + ((h2 - l2) >> 1);
                    uint32_t c = 0;
                    for (uint32_t j = t; j < scnt; j += NT)
                        c += (impBits(__uint_as_float(scv[j])) == thr && sci[j] <= mid) ? 1u : 0u;
                    #pragma unroll
                    for (int o = 1; o < 64; o <<= 1) c += (uint32_t)__shfl_xor((int)c, o);
                    if (ln == 0) sw[w] = c;
                    __syncthreads();
                    uint32_t tot2 = 0;
                    for (int i = 0; i < NW; ++i) tot2 += sw[i];
                    __syncthreads();
                    if (tot2 >= m) h2 = mid; else l2 = mid + 1;
                }
                idxthr = l2;
            }
        }
    }
    // thr/idxthr are exact on BOTH hit and miss paths
    if (t == 0) { meta[b * 8 + 0] = thr; meta[b * 8 + 1] = idxthr; }
}

// ---- pass 3: uniform output stream (src copy | tgt copy | exact mask) ----
__global__ __launch_bounds__(256) void final_kernel(
    const float4* __restrict__ src4, const float4* __restrict__ tgt4,
    const float4* __restrict__ cost4, float4* __restrict__ out4,
    const uint32_t* __restrict__ meta, int s4, int t4, int l2n4) {
    const int idx = blockIdx.x * 256 + threadIdx.x;
    if (idx < s4) { out4[idx] = src4[idx]; return; }
    int r = idx - s4;
    if (r < t4) { out4[idx] = tgt4[r]; return; }
    r -= t4;
    const int b = r >> l2n4;
    const uint32_t thr = meta[b * 8 + 0];
    const uint32_t idxthr = meta[b * 8 + 1];
    const int i = r & ((1 << l2n4) - 1);
    float4 v = cost4[(size_t)b * (1 << l2n4) + i];
    const uint32_t e0 = (uint32_t)i * 4u;
    float4 o;
    uint32_t bx;
    bx = impBits(v.x); o.x = (bx > thr || (bx == thr && e0 + 0 <= idxthr)) ? v.x : 0.0f;
    bx = impBits(v.y); o.y = (bx > thr || (bx == thr && e0 + 1 <= idxthr)) ? v.y : 0.0f;
    bx = impBits(v.z); o.z = (bx > thr || (bx == thr && e0 + 2 <= idxthr)) ? v.z : 0.0f;
    bx = impBits(v.w); o.w = (bx > thr || (bx == thr && e0 + 3 <= idxthr)) ? v.w : 0.0f;
    out4[idx] = o;
}

extern "C" void kernel_launch(void* const* d_in, const int* in_sizes, int n_in,
                              void* d_out, int out_size, void* d_ws, size_t ws_size,
                              hipStream_t stream) {
    const float* src  = (const float*)d_in[0];
    const float* tgt  = (const float*)d_in[1];
    const float* cost = (const float*)d_in[2];
    const int srcN = in_sizes[0];
    const int tgtN = in_sizes[1];
    const int costN = in_sizes[2];
    const int S = 1024, T = 1024;
    const int N = S * T;
    const int B = costN / N;
    const uint32_t K = (uint32_t)(((uint64_t)N * 2ull) / 10ull);  // int(N*0.2)

    float* out = (float*)d_out;

    const int nG = B * GPB;             // 1024 gather blocks
    uint32_t* bcnt  = (uint32_t*)d_ws;                    // nG * 8
    uint32_t* meta  = bcnt + (size_t)nG * 8;              // B * 8
    uint32_t* candv = meta + (size_t)B * 8;               // nG * LCAP
    uint32_t* candi = candv + (size_t)nG * LCAP;          // nG * LCAP

    const int n4 = N / 4;               // 262144 = 2^18
    const int s4 = srcN / 4, t4 = tgtN / 4;
    int l2n4 = 0;
    while ((1 << l2n4) < n4) ++l2n4;

    dim3 blk(256, 1, 1);

    gather_kernel<<<nG, blk, 0, stream>>>(
        (const float4*)cost, bcnt, candv, candi, n4);
    solve_kernel<<<B, NT, 0, stream>>>(bcnt, meta, candv, candi,
                                       (const float4*)cost, n4, K, N);
    const int total4 = s4 + t4 + B * n4;
    final_kernel<<<(total4 + 255) / 256, blk, 0, stream>>>(
        (const float4*)src, (const float4*)tgt, (const float4*)cost,
        (float4*)out, meta, s4, t4, l2n4);
}